// Round 9
// baseline (185.051 us; speedup 1.0000x reference)
//
#include <hip/hip_runtime.h>

// LCSA: dilated local-window self-attention.
// B=2, L=1024, D=512, H=8, HEAD_W=64, KERNEL=16, dilations {1,1,2,2,4,4,8,8},
// MODE=forward -> src(l,k) = l - (15-k)*dil, zero-padded outside [0,L).
//
// R9 fast path:
//   cvt_swz:  fp32->bf16 + per-row XOR chunk swizzle, 1 thread per 8-elem
//             chunk (32B read / 16B write, fully coalesced)
//   gemm_bf16: qkv = x*[Wq|Wk|Wv]^T + bias -> natural row-major bf16
//              (2048 x 16896). EXACT R6 structure: BK=32 single-buffer,
//              16KB LDS, (256,4), grid dim3(136,16) (x%8==0, pad tiles exit).
//              R8's explicit double-buffer REGRESSED (58->64us) - barrier
//              drain is structural (m99/m100 analog); R7's (256,8) spilled
//              acc to scratch (641MB fetch). This is the local optimum.
//   attn_bf16: SINGLE-PASS online-softmax gather (k+v loaded per tap, running
//              m/s/acc rescale) - halves the serial load chain vs 2-pass.
//   gemm_out:  out = attnb*Wo^T + bo, 64x64 tiles, 256 blocks, fp32 out
// Fallback: round-1 fp32 path (8 MB ws).

#define BD 2
#define LL 1024
#define DM 512
#define HH 8
#define KT 16
#define HW 64

#define NQKV 16896          // 512 q + 8192 k + 8192 v

typedef unsigned short u16;
typedef unsigned int u32;
typedef __bf16 bf16x8 __attribute__((ext_vector_type(8)));
typedef float f32x4 __attribute__((ext_vector_type(4)));
typedef unsigned short ushort4v __attribute__((ext_vector_type(4)));
typedef unsigned short ushort8v __attribute__((ext_vector_type(8)));

__constant__ int c_dil[8] = {1, 1, 2, 2, 4, 4, 8, 8};

__device__ __forceinline__ float bf2f(u16 u) {
    return __builtin_bit_cast(float, (u32)u << 16);
}
__device__ __forceinline__ u16 f2bf(float f) {   // round-to-nearest-even
    u32 u = __builtin_bit_cast(u32, f);
    return (u16)((u + 0x7fffu + ((u >> 16) & 1u)) >> 16);
}

// async global->LDS, 16 B per lane; lds dest must be (uniform base + lane*16)
__device__ __forceinline__ void gl_lds16(const u16* g, u16* l) {
    __builtin_amdgcn_global_load_lds(
        (__attribute__((address_space(1))) void*)g,
        (__attribute__((address_space(3))) void*)l, 16, 0, 0);
}

// ===========================================================================
// Fused qkv projection GEMM (R6 structure, verbatim).
// C(2048 x NQKV bf16) = x(2048x512) * [Wq|Wk|Wv]^T + bias.
// 128x128 tile, BK=32, 4 waves (64x64 each), 16x16x32 MFMA, swizzled A/B.
// ===========================================================================
__global__ __launch_bounds__(256, 4) void gemm_bf16(
    const u16* __restrict__ A, const u16* __restrict__ Bm,
    const float* __restrict__ bq, const float* __restrict__ bk,
    const float* __restrict__ bv, u16* __restrict__ C)
{
    const int m0 = blockIdx.y << 7;
    const int n0 = blockIdx.x << 7;
    if (n0 >= NQKV) return;             // pad tiles

    __shared__ u16 As[128 * 32];
    __shared__ u16 Bs[128 * 32];

    const int tid  = threadIdx.x;
    const int wave = tid >> 6, lane = tid & 63;
    const int r0 = tid >> 2;            // staging row 0..63 (round 0)
    const int cc = (tid & 3) << 3;      // staging k-offset (elements)
    const int mw = (wave >> 1) << 6;
    const int nw = (wave & 1) << 6;
    const int lr = lane & 15;
    const int qg = lane >> 4;
    const int ksw = ((qg ^ ((lr >> 1) & 3)) << 3);   // swizzled chunk

    const u16* Ag = A  + (size_t)(m0 + r0) * DM + cc;
    const u16* Bg = Bm + (size_t)(n0 + r0) * DM + cc;
    u16* lA = &As[0] + tid * 8;
    u16* lB = &Bs[0] + tid * 8;

    f32x4 acc[4][4];
#pragma unroll
    for (int i = 0; i < 4; ++i)
#pragma unroll
        for (int j = 0; j < 4; ++j) acc[i][j] = (f32x4){0.f, 0.f, 0.f, 0.f};

    for (int k0 = 0; k0 < DM; k0 += 32) {
        gl_lds16(Ag + k0, lA);
        gl_lds16(Ag + k0 + (size_t)64 * DM, lA + 64 * 32);
        gl_lds16(Bg + k0, lB);
        gl_lds16(Bg + k0 + (size_t)64 * DM, lB + 64 * 32);
        __syncthreads();

        bf16x8 af[4], bfr[4];
#pragma unroll
        for (int i = 0; i < 4; ++i)
            af[i] = *(const bf16x8*)&As[(mw + (i << 4) + lr) * 32 + ksw];
#pragma unroll
        for (int j = 0; j < 4; ++j)
            bfr[j] = *(const bf16x8*)&Bs[(nw + (j << 4) + lr) * 32 + ksw];
#pragma unroll
        for (int i = 0; i < 4; ++i)
#pragma unroll
            for (int j = 0; j < 4; ++j)
                acc[i][j] = __builtin_amdgcn_mfma_f32_16x16x32_bf16(
                    af[i], bfr[j], acc[i][j], 0, 0, 0);
        __syncthreads();
    }

    // bias region is tile-uniform (tiles 0..3 q, 4..67 k, 68..131 v)
    const float* bias; int cb;
    if      (n0 <  512) { bias = bq; cb = 0;    }
    else if (n0 < 8704) { bias = bk; cb = 512;  }
    else                { bias = bv; cb = 8704; }

    // C row = m0+mw+16i+4qg+r, col = n0+nw+16j+lr
#pragma unroll
    for (int i = 0; i < 4; ++i) {
        const int rowb = m0 + mw + (i << 4) + (qg << 2);
#pragma unroll
        for (int j = 0; j < 4; ++j) {
            const int col = n0 + nw + (j << 4) + lr;
            const float bs = bias[col - cb];
#pragma unroll
            for (int r = 0; r < 4; ++r)
                C[(size_t)(rowb + r) * NQKV + col] = f2bf(acc[i][j][r] + bs);
        }
    }
}

// ===========================================================================
// Output projection: out(2048x512 fp32) = attnb(2048x512 swz) * Wo^T(512x512
// swz) + bo. 64x64 tiles, grid (8,32) = 256 blocks, 4 waves (16x64 each).
// ===========================================================================
__global__ __launch_bounds__(256, 4) void gemm_out(
    const u16* __restrict__ A, const u16* __restrict__ Bm,
    const float* __restrict__ bias, float* __restrict__ C)
{
    __shared__ u16 As[64 * 32];
    __shared__ u16 Bs[64 * 32];

    const int tid  = threadIdx.x;
    const int wave = tid >> 6, lane = tid & 63;
    const int m0 = blockIdx.y << 6, n0 = blockIdx.x << 6;
    const int r0 = tid >> 2, cc = (tid & 3) << 3;
    const int mw = wave << 4;           // wave's 16-row band
    const int lr = lane & 15, qg = lane >> 4;
    const int ksw = ((qg ^ ((lr >> 1) & 3)) << 3);

    const u16* Ag = A  + (size_t)(m0 + r0) * DM + cc;
    const u16* Bg = Bm + (size_t)(n0 + r0) * DM + cc;
    u16* lA = &As[0] + tid * 8;
    u16* lB = &Bs[0] + tid * 8;

    f32x4 acc[4];
#pragma unroll
    for (int j = 0; j < 4; ++j) acc[j] = (f32x4){0.f, 0.f, 0.f, 0.f};

    for (int k0 = 0; k0 < DM; k0 += 32) {
        gl_lds16(Ag + k0, lA);
        gl_lds16(Bg + k0, lB);
        __syncthreads();
        bf16x8 af = *(const bf16x8*)&As[(mw + lr) * 32 + ksw];
#pragma unroll
        for (int j = 0; j < 4; ++j) {
            bf16x8 bfr = *(const bf16x8*)&Bs[((j << 4) + lr) * 32 + ksw];
            acc[j] = __builtin_amdgcn_mfma_f32_16x16x32_bf16(af, bfr, acc[j], 0, 0, 0);
        }
        __syncthreads();
    }

    // C row = m0+mw+4qg+r, col = n0+16j+lr
#pragma unroll
    for (int j = 0; j < 4; ++j) {
        const int col = n0 + (j << 4) + lr;
        const float bs = bias[col];
#pragma unroll
        for (int r = 0; r < 4; ++r)
            C[(size_t)(m0 + mw + (qg << 2) + r) * DM + col] = acc[j][r] + bs;
    }
}

// ===========================================================================
// fp32 -> bf16 + swizzle. One thread per 8-elem chunk: 32B read, 16B write,
// both coalesced (the XOR permutes chunks within a 64B line).
// Chunks (row*64): x 131072 | [Wq|Wk|Wv] 1081344 | Wo 32768
// Total 1245184 = 4864 blocks x 256.
// ===========================================================================
__global__ void cvt_swz(const float* __restrict__ x,  const float* __restrict__ Wq,
                        const float* __restrict__ Wk, const float* __restrict__ Wv,
                        const float* __restrict__ Wo,
                        u16* __restrict__ xb, u16* __restrict__ wb,
                        u16* __restrict__ wob)
{
    const int i = blockIdx.x * 256 + threadIdx.x;
    const float* src; u16* dst; int t;
    if (i < 131072) {
        t = i;
        src = x;  dst = xb;
    } else if (i < 1212416) {
        t = i - 131072;
        const int row = t >> 6;
        if      (row <  512) src = Wq;
        else if (row < 8704) src = Wk - (size_t)512 * DM;
        else                 src = Wv - (size_t)8704 * DM;
        dst = wb;
    } else {
        t = i - 1212416;
        src = Wo; dst = wob;
    }
    const int row = t >> 6;              // 64 chunks per row
    const int c8  = t & 63;              // output chunk within row
    const int s   = (row >> 1) & 3;
    const int oc  = (c8 & ~3) | ((c8 & 3) ^ s);   // source chunk
    const float* p = src + (size_t)row * DM + (oc << 3);
    float4 v0 = *(const float4*)p;
    float4 v1 = *(const float4*)(p + 4);
    ushort8v o = { f2bf(v0.x), f2bf(v0.y), f2bf(v0.z), f2bf(v0.w),
                   f2bf(v1.x), f2bf(v1.y), f2bf(v1.z), f2bf(v1.w) };
    *(ushort8v*)(dst + (size_t)row * DM + (c8 << 3)) = o;
}

// ===========================================================================
// attention gather, SINGLE-PASS online softmax.
// 256 thr = 32 l's x 8 o-groups, grid = B*H*(L/32) = 512.
// Per tap: load k-row AND v-row, logit via 3 shfl_xor (8-lane group),
// online-update (m, s, acc). Reads q/k/v from natural qkv (stride NQKV);
// writes attnb SWIZZLED (A-matrix of the out-projection GEMM).
// ===========================================================================
__global__ __launch_bounds__(256, 8) void attn_bf16(
    const u16* __restrict__ qkv,    // (B*L, NQKV) bf16
    const float* __restrict__ bk,   // (H,K,64) fp32
    const float* __restrict__ bv,
    u16* __restrict__ attnb)        // (B,L,512) bf16 swizzled
{
    const int tid = threadIdx.x;
    const int j  = tid & 7;          // o-group (8 o's)
    const int ll = tid >> 3;         // 0..31
    const int bid = blockIdx.x;
    const int h = bid & 7;
    const int t = (bid >> 3) & 31;
    const int b = bid >> 8;
    const int l = (t << 5) + ll;
    const int dil = c_dil[h];

    const int hko = h * (KT * HW);   // head offset within k/v region

    float qf[8];
    {
        ushort8v qv = *(const ushort8v*)(qkv + (size_t)(b * LL + l) * NQKV
                                         + h * HW + (j << 3));
#pragma unroll
        for (int z = 0; z < 8; ++z) qf[z] = bf2f(qv[z]);
    }

    float m = -3.0e38f, s = 0.f;
    float acc[8];
#pragma unroll
    for (int z = 0; z < 8; ++z) acc[z] = 0.f;

#pragma unroll
    for (int k = 0; k < KT; ++k) {
        const int src = l - (KT - 1 - k) * dil;
        float p = 0.f;
        float vf[8];
        if (src >= 0) {
            const u16* rowp = qkv + (size_t)(b * LL + src) * NQKV + hko + (j << 3);
            ushort8v kv = *(const ushort8v*)(rowp + 512 + k * HW);
            ushort8v vv = *(const ushort8v*)(rowp + 8704 + k * HW);
#pragma unroll
            for (int z = 0; z < 8; ++z) {
                p += qf[z] * bf2f(kv[z]);
                vf[z] = bf2f(vv[z]);
            }
        } else {
            const float* bkp = bk + hko + k * HW + (j << 3);
            const float* bvp = bv + hko + k * HW + (j << 3);
#pragma unroll
            for (int z = 0; z < 8; ++z) {
                p += qf[z] * bkp[z];
                vf[z] = bvp[z];
            }
        }
        p += __shfl_xor(p, 1);
        p += __shfl_xor(p, 2);
        p += __shfl_xor(p, 4);

        const float mn = fmaxf(m, p);
        const float alpha = __expf(m - mn);   // first tap: exp(-inf)=0
        const float e = __expf(p - mn);
        s = s * alpha + e;
#pragma unroll
        for (int z = 0; z < 8; ++z)
            acc[z] = acc[z] * alpha + e * vf[z];
        m = mn;
    }

    const float inv = 0.125f / s;
    ushort8v o;
#pragma unroll
    for (int z = 0; z < 8; ++z) o[z] = f2bf(acc[z] * inv);
    const int row = b * LL + l;
    const int k8 = h * 8 + j;
    const int sw = ((k8 & 3) ^ ((l >> 1) & 3)) << 3;
    *(ushort8v*)(attnb + (size_t)row * DM + ((k8 >> 2) << 5) + sw) = o;
}

// ===========================================================================
// ------------------- round-1 fp32 fallback (small ws) ----------------------
// ===========================================================================
__global__ __launch_bounds__(256, 2) void gemm_nt_bias(
    const float* __restrict__ A, const float* __restrict__ Bm,
    const float* __restrict__ bias, float* __restrict__ C,
    int M, int N, int Kd)
{
    __shared__ float As[16][68];
    __shared__ float Bs[16][68];
    const int tid = threadIdx.x;
    const int tx = tid & 15, ty = tid >> 4;
    const int r0 = blockIdx.y << 6, c0 = blockIdx.x << 6;
    const int lr = tid >> 2, k4 = (tid & 3) << 2;
    const float* Ap = A  + (size_t)(r0 + lr) * Kd + k4;
    const float* Bp = Bm + (size_t)(c0 + lr) * Kd + k4;
    float acc[4][4];
#pragma unroll
    for (int i = 0; i < 4; ++i)
#pragma unroll
        for (int j = 0; j < 4; ++j) acc[i][j] = 0.f;
    for (int d0 = 0; d0 < Kd; d0 += 16) {
        float4 av = *(const float4*)(Ap + d0);
        float4 bv = *(const float4*)(Bp + d0);
        As[k4 + 0][lr] = av.x; As[k4 + 1][lr] = av.y;
        As[k4 + 2][lr] = av.z; As[k4 + 3][lr] = av.w;
        Bs[k4 + 0][lr] = bv.x; Bs[k4 + 1][lr] = bv.y;
        Bs[k4 + 2][lr] = bv.z; Bs[k4 + 3][lr] = bv.w;
        __syncthreads();
#pragma unroll
        for (int dd = 0; dd < 16; ++dd) {
            float4 a4 = *(const float4*)&As[dd][ty << 2];
            float4 b4 = *(const float4*)&Bs[dd][tx << 2];
            float ar[4] = {a4.x, a4.y, a4.z, a4.w};
            float br[4] = {b4.x, b4.y, b4.z, b4.w};
#pragma unroll
            for (int i = 0; i < 4; ++i)
#pragma unroll
                for (int j = 0; j < 4; ++j)
                    acc[i][j] = fmaf(ar[i], br[j], acc[i][j]);
        }
        __syncthreads();
    }
#pragma unroll
    for (int i = 0; i < 4; ++i) {
        float4 o;
        const int c = c0 + (tx << 2);
        o.x = acc[i][0] + bias[c + 0];
        o.y = acc[i][1] + bias[c + 1];
        o.z = acc[i][2] + bias[c + 2];
        o.w = acc[i][3] + bias[c + 3];
        *(float4*)&C[(size_t)(r0 + (ty << 2) + i) * N + c] = o;
    }
}

__device__ __forceinline__ void tile_gemm_f32(
    const float* __restrict__ xb, int src, bool ok,
    const float* __restrict__ wrow,
    int lr, int k4, int tx, int ty,
    float (&As)[16][68], float (&Ws)[16][68], float (&acc)[4][4])
{
#pragma unroll
    for (int i = 0; i < 4; ++i)
#pragma unroll
        for (int j = 0; j < 4; ++j) acc[i][j] = 0.f;
    const float* xrow = xb + (size_t)(ok ? src : 0) * DM + k4;
    for (int d0 = 0; d0 < DM; d0 += 16) {
        float4 av = make_float4(0.f, 0.f, 0.f, 0.f);
        if (ok) av = *(const float4*)(xrow + d0);
        float4 wv = *(const float4*)(wrow + d0);
        As[k4 + 0][lr] = av.x; As[k4 + 1][lr] = av.y;
        As[k4 + 2][lr] = av.z; As[k4 + 3][lr] = av.w;
        Ws[k4 + 0][lr] = wv.x; Ws[k4 + 1][lr] = wv.y;
        Ws[k4 + 2][lr] = wv.z; Ws[k4 + 3][lr] = wv.w;
        __syncthreads();
#pragma unroll
        for (int dd = 0; dd < 16; ++dd) {
            float4 a4 = *(const float4*)&As[dd][ty << 2];
            float4 b4 = *(const float4*)&Ws[dd][tx << 2];
            float ar[4] = {a4.x, a4.y, a4.z, a4.w};
            float br[4] = {b4.x, b4.y, b4.z, b4.w};
#pragma unroll
            for (int i = 0; i < 4; ++i)
#pragma unroll
                for (int j = 0; j < 4; ++j)
                    acc[i][j] = fmaf(ar[i], br[j], acc[i][j]);
        }
        __syncthreads();
    }
}

__global__ __launch_bounds__(256, 2) void attn_kernel(
    const float* __restrict__ x, const float* __restrict__ q,
    const float* __restrict__ Wk, const float* __restrict__ bk,
    const float* __restrict__ Wv, const float* __restrict__ bv,
    float* __restrict__ attn)
{
    __shared__ float As[16][68];
    __shared__ float Ws[16][68];
    __shared__ float qs[64][68];
    __shared__ float lg[64][17];
    __shared__ float red[64][17];
    const int tid = threadIdx.x;
    const int tx = tid & 15, ty = tid >> 4;
    const int bid = blockIdx.x;
    const int h = bid & 7, t = (bid >> 3) & 15, b = bid >> 7;
    const int l0 = t << 6;
    const int dil = c_dil[h];
    const int lr = tid >> 2, k4 = (tid & 3) << 2;
    for (int i = tid; i < 64 * 16; i += 256) {
        int l = i >> 4, o4 = (i & 15) << 2;
        float4 v = *(const float4*)&q[((size_t)(b * LL + l0 + l) * HH + h) * HW + o4];
        *(float4*)&qs[l][o4] = v;
    }
    const float* xb  = x  + (size_t)b * LL * DM;
    const float* Wkh = Wk + (size_t)h * KT * HW * DM;
    const float* Wvh = Wv + (size_t)h * KT * HW * DM;
    const float* bkh = bk + h * KT * HW;
    const float* bvh = bv + h * KT * HW;
    float acc[4][4];
    for (int kk = 0; kk < KT; ++kk) {
        const int src = l0 + lr - (KT - 1 - kk) * dil;
        const bool ok = (src >= 0) && (src < LL);
        tile_gemm_f32(xb, src, ok, Wkh + (size_t)(kk * HW + lr) * DM + k4,
                      lr, k4, tx, ty, As, Ws, acc);
        const float* bkp = bkh + kk * HW + (tx << 2);
#pragma unroll
        for (int i = 0; i < 4; ++i) {
            float p = 0.f;
#pragma unroll
            for (int j = 0; j < 4; ++j)
                p += (acc[i][j] + bkp[j]) * qs[(ty << 2) + i][(tx << 2) + j];
            red[(ty << 2) + i][tx] = p;
        }
        __syncthreads();
        if (tid < 64) {
            float s = 0.f;
#pragma unroll
            for (int u = 0; u < 16; ++u) s += red[tid][u];
            lg[tid][kk] = s;
        }
        __syncthreads();
    }
    if (tid < 64) {
        float m = lg[tid][0];
#pragma unroll
        for (int u = 1; u < KT; ++u) m = fmaxf(m, lg[tid][u]);
        float s = 0.f;
#pragma unroll
        for (int u = 0; u < KT; ++u) {
            float e = expf(lg[tid][u] - m);
            lg[tid][u] = e; s += e;
        }
        float inv = 1.f / s;
#pragma unroll
        for (int u = 0; u < KT; ++u) lg[tid][u] *= inv;
    }
    __syncthreads();
    float vacc[4][4];
#pragma unroll
    for (int i = 0; i < 4; ++i)
#pragma unroll
        for (int j = 0; j < 4; ++j) vacc[i][j] = 0.f;
    for (int kk = 0; kk < KT; ++kk) {
        const int src = l0 + lr - (KT - 1 - kk) * dil;
        const bool ok = (src >= 0) && (src < LL);
        tile_gemm_f32(xb, src, ok, Wvh + (size_t)(kk * HW + lr) * DM + k4,
                      lr, k4, tx, ty, As, Ws, acc);
        const float* bvp = bvh + kk * HW + (tx << 2);
#pragma unroll
        for (int i = 0; i < 4; ++i) {
            float sc = lg[(ty << 2) + i][kk];
#pragma unroll
            for (int j = 0; j < 4; ++j)
                vacc[i][j] = fmaf(sc, acc[i][j] + bvp[j], vacc[i][j]);
        }
    }
#pragma unroll
    for (int i = 0; i < 4; ++i) {
        float4 o;
        o.x = vacc[i][0] * 0.125f;
        o.y = vacc[i][1] * 0.125f;
        o.z = vacc[i][2] * 0.125f;
        o.w = vacc[i][3] * 0.125f;
        *(float4*)&attn[((size_t)(b * LL + l0 + (ty << 2) + i) * HH + h) * HW + (tx << 2)] = o;
    }
}

// ===========================================================================
extern "C" void kernel_launch(void* const* d_in, const int* in_sizes, int n_in,
                              void* d_out, int out_size, void* d_ws, size_t ws_size,
                              hipStream_t stream)
{
    const float* x  = (const float*)d_in[0];
    const float* Wq = (const float*)d_in[1];
    const float* bq = (const float*)d_in[2];
    const float* Wk = (const float*)d_in[3];
    const float* bk = (const float*)d_in[4];
    const float* Wv = (const float*)d_in[5];
    const float* bv = (const float*)d_in[6];
    const float* Wo = (const float*)d_in[7];
    const float* bo = (const float*)d_in[8];
    float* out = (float*)d_out;

    const int M = BD * LL;  // 2048

    // ws layout (ushort elements) for the fast path
    const size_t N_X   = (size_t)BD * LL * DM;            //  1,048,576
    const size_t N_WB  = (size_t)NQKV * DM;               //  8,650,752
    const size_t N_WO  = (size_t)DM * DM;                 //    262,144
    const size_t N_QKV = (size_t)M * NQKV;                // 34,603,008
    const size_t NEED  = (N_X + N_WB + N_WO + N_QKV + N_X) * 2;

    if (ws_size >= NEED) {
        u16* xb    = (u16*)d_ws;
        u16* wb    = xb    + N_X;      // [Wq|Wk|Wv] swizzled, 16896 x 512
        u16* wob   = wb    + N_WB;
        u16* qkv   = wob   + N_WO;     // natural row-major 2048 x 16896
        u16* attnb = qkv   + N_QKV;

        cvt_swz<<<4864, 256, 0, stream>>>(x, Wq, Wk, Wv, Wo, xb, wb, wob);

        // qkv = x * [Wq|Wk|Wv]^T + bias (natural layout)
        gemm_bf16<<<dim3(136, 16), 256, 0, stream>>>(
            xb, wb, bq, bk, bv, qkv);

        // single-pass online-softmax gather -> attnb (swizzled)
        attn_bf16<<<BD * HH * (LL / 32), 256, 0, stream>>>(
            qkv, bk, bv, attnb);

        // out = attnb * Wo^T + bo -> fp32
        gemm_out<<<dim3(8, 32), 256, 0, stream>>>(attnb, wob, bo, out);
    } else {
        // fp32 fallback (round-1 path, 8 MB ws)
        float* qws = (float*)d_ws;
        float* aws = qws + (size_t)BD * LL * HH * HW;
        gemm_nt_bias<<<dim3((HH * HW) / 64, M / 64), 256, 0, stream>>>(
            x, Wq, bq, qws, M, HH * HW, DM);
        attn_kernel<<<BD * HH * (LL / 64), 256, 0, stream>>>(
            x, qws, Wk, bk, Wv, bv, aws);
        gemm_nt_bias<<<dim3(DM / 64, M / 64), 256, 0, stream>>>(
            aws, Wo, bo, out, M, DM, HH * HW);
    }
}

// Round 10
// 169.978 us; speedup vs baseline: 1.0887x; 1.0887x over previous
//
#include <hip/hip_runtime.h>

// LCSA: dilated local-window self-attention.
// B=2, L=1024, D=512, H=8, HEAD_W=64, KERNEL=16, dilations {1,1,2,2,4,4,8,8},
// MODE=forward -> src(l,k) = l - (15-k)*dil, zero-padded outside [0,L).
//
// R10 fast path:
//   cvt_swz:  fp32->bf16 + per-row XOR chunk swizzle (coalesced both sides)
//   gemm_bf16: qkv = x*[Wq|Wk|Wv]^T + bias -> natural row-major bf16
//              (2048 x 16896). R6 structure (local optimum: BK=32 single-buf,
//              16KB LDS, (256,4), grid 136x16 pad-exit). Measured 58us.
//   attn_bf16: TWO-PHASE register-resident gather: all 16 k-loads in flight
//              -> logits -> reg softmax -> all 16 v-loads in flight -> acc.
//              (256,4): R9's (256,8) capped VGPR at 32 and serialized loads
//              (65us @ 28% HBM on a 66MB compulsory stream).
//   gemm_out:  out = attnb*Wo^T + bo, 64x64 tiles, 256 blocks, fp32 out
// Fallback: round-1 fp32 path (8 MB ws).

#define BD 2
#define LL 1024
#define DM 512
#define HH 8
#define KT 16
#define HW 64

#define NQKV 16896          // 512 q + 8192 k + 8192 v

typedef unsigned short u16;
typedef unsigned int u32;
typedef __bf16 bf16x8 __attribute__((ext_vector_type(8)));
typedef float f32x4 __attribute__((ext_vector_type(4)));
typedef unsigned short ushort4v __attribute__((ext_vector_type(4)));
typedef unsigned short ushort8v __attribute__((ext_vector_type(8)));

__constant__ int c_dil[8] = {1, 1, 2, 2, 4, 4, 8, 8};

__device__ __forceinline__ float bf2f(u16 u) {
    return __builtin_bit_cast(float, (u32)u << 16);
}
__device__ __forceinline__ u16 f2bf(float f) {   // round-to-nearest-even
    u32 u = __builtin_bit_cast(u32, f);
    return (u16)((u + 0x7fffu + ((u >> 16) & 1u)) >> 16);
}

// async global->LDS, 16 B per lane; lds dest must be (uniform base + lane*16)
__device__ __forceinline__ void gl_lds16(const u16* g, u16* l) {
    __builtin_amdgcn_global_load_lds(
        (__attribute__((address_space(1))) void*)g,
        (__attribute__((address_space(3))) void*)l, 16, 0, 0);
}

// ===========================================================================
// Fused qkv projection GEMM (R6 structure, verbatim).
// C(2048 x NQKV bf16) = x(2048x512) * [Wq|Wk|Wv]^T + bias.
// 128x128 tile, BK=32, 4 waves (64x64 each), 16x16x32 MFMA, swizzled A/B.
// ===========================================================================
__global__ __launch_bounds__(256, 4) void gemm_bf16(
    const u16* __restrict__ A, const u16* __restrict__ Bm,
    const float* __restrict__ bq, const float* __restrict__ bk,
    const float* __restrict__ bv, u16* __restrict__ C)
{
    const int m0 = blockIdx.y << 7;
    const int n0 = blockIdx.x << 7;
    if (n0 >= NQKV) return;             // pad tiles

    __shared__ u16 As[128 * 32];
    __shared__ u16 Bs[128 * 32];

    const int tid  = threadIdx.x;
    const int wave = tid >> 6, lane = tid & 63;
    const int r0 = tid >> 2;            // staging row 0..63 (round 0)
    const int cc = (tid & 3) << 3;      // staging k-offset (elements)
    const int mw = (wave >> 1) << 6;
    const int nw = (wave & 1) << 6;
    const int lr = lane & 15;
    const int qg = lane >> 4;
    const int ksw = ((qg ^ ((lr >> 1) & 3)) << 3);   // swizzled chunk

    const u16* Ag = A  + (size_t)(m0 + r0) * DM + cc;
    const u16* Bg = Bm + (size_t)(n0 + r0) * DM + cc;
    u16* lA = &As[0] + tid * 8;
    u16* lB = &Bs[0] + tid * 8;

    f32x4 acc[4][4];
#pragma unroll
    for (int i = 0; i < 4; ++i)
#pragma unroll
        for (int j = 0; j < 4; ++j) acc[i][j] = (f32x4){0.f, 0.f, 0.f, 0.f};

    for (int k0 = 0; k0 < DM; k0 += 32) {
        gl_lds16(Ag + k0, lA);
        gl_lds16(Ag + k0 + (size_t)64 * DM, lA + 64 * 32);
        gl_lds16(Bg + k0, lB);
        gl_lds16(Bg + k0 + (size_t)64 * DM, lB + 64 * 32);
        __syncthreads();

        bf16x8 af[4], bfr[4];
#pragma unroll
        for (int i = 0; i < 4; ++i)
            af[i] = *(const bf16x8*)&As[(mw + (i << 4) + lr) * 32 + ksw];
#pragma unroll
        for (int j = 0; j < 4; ++j)
            bfr[j] = *(const bf16x8*)&Bs[(nw + (j << 4) + lr) * 32 + ksw];
#pragma unroll
        for (int i = 0; i < 4; ++i)
#pragma unroll
            for (int j = 0; j < 4; ++j)
                acc[i][j] = __builtin_amdgcn_mfma_f32_16x16x32_bf16(
                    af[i], bfr[j], acc[i][j], 0, 0, 0);
        __syncthreads();
    }

    // bias region is tile-uniform (tiles 0..3 q, 4..67 k, 68..131 v)
    const float* bias; int cb;
    if      (n0 <  512) { bias = bq; cb = 0;    }
    else if (n0 < 8704) { bias = bk; cb = 512;  }
    else                { bias = bv; cb = 8704; }

    // C row = m0+mw+16i+4qg+r, col = n0+nw+16j+lr
#pragma unroll
    for (int i = 0; i < 4; ++i) {
        const int rowb = m0 + mw + (i << 4) + (qg << 2);
#pragma unroll
        for (int j = 0; j < 4; ++j) {
            const int col = n0 + nw + (j << 4) + lr;
            const float bs = bias[col - cb];
#pragma unroll
            for (int r = 0; r < 4; ++r)
                C[(size_t)(rowb + r) * NQKV + col] = f2bf(acc[i][j][r] + bs);
        }
    }
}

// ===========================================================================
// Output projection: out(2048x512 fp32) = attnb(2048x512 swz) * Wo^T(512x512
// swz) + bo. 64x64 tiles, grid (8,32) = 256 blocks, 4 waves (16x64 each).
// ===========================================================================
__global__ __launch_bounds__(256, 4) void gemm_out(
    const u16* __restrict__ A, const u16* __restrict__ Bm,
    const float* __restrict__ bias, float* __restrict__ C)
{
    __shared__ u16 As[64 * 32];
    __shared__ u16 Bs[64 * 32];

    const int tid  = threadIdx.x;
    const int wave = tid >> 6, lane = tid & 63;
    const int m0 = blockIdx.y << 6, n0 = blockIdx.x << 6;
    const int r0 = tid >> 2, cc = (tid & 3) << 3;
    const int mw = wave << 4;           // wave's 16-row band
    const int lr = lane & 15, qg = lane >> 4;
    const int ksw = ((qg ^ ((lr >> 1) & 3)) << 3);

    const u16* Ag = A  + (size_t)(m0 + r0) * DM + cc;
    const u16* Bg = Bm + (size_t)(n0 + r0) * DM + cc;
    u16* lA = &As[0] + tid * 8;
    u16* lB = &Bs[0] + tid * 8;

    f32x4 acc[4];
#pragma unroll
    for (int j = 0; j < 4; ++j) acc[j] = (f32x4){0.f, 0.f, 0.f, 0.f};

    for (int k0 = 0; k0 < DM; k0 += 32) {
        gl_lds16(Ag + k0, lA);
        gl_lds16(Bg + k0, lB);
        __syncthreads();
        bf16x8 af = *(const bf16x8*)&As[(mw + lr) * 32 + ksw];
#pragma unroll
        for (int j = 0; j < 4; ++j) {
            bf16x8 bfr = *(const bf16x8*)&Bs[((j << 4) + lr) * 32 + ksw];
            acc[j] = __builtin_amdgcn_mfma_f32_16x16x32_bf16(af, bfr, acc[j], 0, 0, 0);
        }
        __syncthreads();
    }

    // C row = m0+mw+4qg+r, col = n0+16j+lr
#pragma unroll
    for (int j = 0; j < 4; ++j) {
        const int col = n0 + (j << 4) + lr;
        const float bs = bias[col];
#pragma unroll
        for (int r = 0; r < 4; ++r)
            C[(size_t)(m0 + mw + (qg << 2) + r) * DM + col] = acc[j][r] + bs;
    }
}

// ===========================================================================
// fp32 -> bf16 + swizzle. One thread per 8-elem chunk: 32B read, 16B write,
// both coalesced (the XOR permutes chunks within a 64B line).
// Chunks (row*64): x 131072 | [Wq|Wk|Wv] 1081344 | Wo 32768
// Total 1245184 = 4864 blocks x 256.
// ===========================================================================
__global__ void cvt_swz(const float* __restrict__ x,  const float* __restrict__ Wq,
                        const float* __restrict__ Wk, const float* __restrict__ Wv,
                        const float* __restrict__ Wo,
                        u16* __restrict__ xb, u16* __restrict__ wb,
                        u16* __restrict__ wob)
{
    const int i = blockIdx.x * 256 + threadIdx.x;
    const float* src; u16* dst; int t;
    if (i < 131072) {
        t = i;
        src = x;  dst = xb;
    } else if (i < 1212416) {
        t = i - 131072;
        const int row = t >> 6;
        if      (row <  512) src = Wq;
        else if (row < 8704) src = Wk - (size_t)512 * DM;
        else                 src = Wv - (size_t)8704 * DM;
        dst = wb;
    } else {
        t = i - 1212416;
        src = Wo; dst = wob;
    }
    const int row = t >> 6;              // 64 chunks per row
    const int c8  = t & 63;              // output chunk within row
    const int s   = (row >> 1) & 3;
    const int oc  = (c8 & ~3) | ((c8 & 3) ^ s);   // source chunk
    const float* p = src + (size_t)row * DM + (oc << 3);
    float4 v0 = *(const float4*)p;
    float4 v1 = *(const float4*)(p + 4);
    ushort8v o = { f2bf(v0.x), f2bf(v0.y), f2bf(v0.z), f2bf(v0.w),
                   f2bf(v1.x), f2bf(v1.y), f2bf(v1.z), f2bf(v1.w) };
    *(ushort8v*)(dst + (size_t)row * DM + (c8 << 3)) = o;
}

// ===========================================================================
// attention gather, TWO-PHASE register-resident.
// 256 thr = 32 l's x 8 o-groups, grid = B*H*(L/32) = 512.
// Phase 1: all 16 k-row loads issued back-to-back (independent addresses,
//          max loads-in-flight), 16 logits via 3x shfl_xor each.
// Softmax entirely in registers.
// Phase 2: all 16 v-row loads issued, weighted accumulate.
// (256,4) -> 128-VGPR budget: kr[16] payload is 64 VGPRs; R9's (256,8)
// forced VGPR=32 and serialized the stream (65us @ 28% HBM).
// ===========================================================================
__global__ __launch_bounds__(256, 4) void attn_bf16(
    const u16* __restrict__ qkv,    // (B*L, NQKV) bf16
    const float* __restrict__ bk,   // (H,K,64) fp32
    const float* __restrict__ bv,
    u16* __restrict__ attnb)        // (B,L,512) bf16 swizzled
{
    const int tid = threadIdx.x;
    const int j  = tid & 7;          // o-group (8 o's)
    const int ll = tid >> 3;         // 0..31
    const int bid = blockIdx.x;
    const int h = bid & 7;
    const int t = (bid >> 3) & 31;
    const int b = bid >> 8;
    const int l = (t << 5) + ll;
    const int dil = c_dil[h];

    const int hko = h * (KT * HW);   // head offset within k/v region
    const size_t rowbase = (size_t)(b * LL) * NQKV + hko + (j << 3);

    float qf[8];
    {
        ushort8v qv = *(const ushort8v*)(qkv + (size_t)(b * LL + l) * NQKV
                                         + h * HW + (j << 3));
#pragma unroll
        for (int z = 0; z < 8; ++z) qf[z] = bf2f(qv[z]);
    }

    // ---- phase 1: all k loads in flight, then logits ----
    ushort8v kr[KT];
#pragma unroll
    for (int k = 0; k < KT; ++k) {
        const int src = l - (KT - 1 - k) * dil;
        if (src >= 0)
            kr[k] = *(const ushort8v*)(qkv + rowbase + (size_t)src * NQKV
                                       + 512 + k * HW);
    }

    float lg[KT];
#pragma unroll
    for (int k = 0; k < KT; ++k) {
        const int src = l - (KT - 1 - k) * dil;
        float p = 0.f;
        if (src >= 0) {
#pragma unroll
            for (int z = 0; z < 8; ++z) p += qf[z] * bf2f(kr[k][z]);
        } else {
            const float* bkp = bk + hko + k * HW + (j << 3);
#pragma unroll
            for (int z = 0; z < 8; ++z) p += qf[z] * bkp[z];
        }
        p += __shfl_xor(p, 1);
        p += __shfl_xor(p, 2);
        p += __shfl_xor(p, 4);
        lg[k] = p;
    }

    // ---- softmax in registers ----
    float m = lg[0];
#pragma unroll
    for (int k = 1; k < KT; ++k) m = fmaxf(m, lg[k]);
    float s = 0.f;
#pragma unroll
    for (int k = 0; k < KT; ++k) { lg[k] = __expf(lg[k] - m); s += lg[k]; }
    const float inv = 1.f / s;

    // ---- phase 2: all v loads in flight, weighted accumulate ----
    ushort8v vr[KT];
#pragma unroll
    for (int k = 0; k < KT; ++k) {
        const int src = l - (KT - 1 - k) * dil;
        if (src >= 0)
            vr[k] = *(const ushort8v*)(qkv + rowbase + (size_t)src * NQKV
                                       + 8704 + k * HW);
    }

    float acc[8];
#pragma unroll
    for (int z = 0; z < 8; ++z) acc[z] = 0.f;
#pragma unroll
    for (int k = 0; k < KT; ++k) {
        const int src = l - (KT - 1 - k) * dil;
        const float sc = lg[k] * inv;
        if (src >= 0) {
#pragma unroll
            for (int z = 0; z < 8; ++z) acc[z] = fmaf(sc, bf2f(vr[k][z]), acc[z]);
        } else {
            const float* bvp = bv + hko + k * HW + (j << 3);
#pragma unroll
            for (int z = 0; z < 8; ++z) acc[z] = fmaf(sc, bvp[z], acc[z]);
        }
    }

    ushort8v o;
#pragma unroll
    for (int z = 0; z < 8; ++z) o[z] = f2bf(acc[z] * 0.125f);
    const int row = b * LL + l;
    const int k8 = h * 8 + j;
    const int sw = ((k8 & 3) ^ ((l >> 1) & 3)) << 3;
    *(ushort8v*)(attnb + (size_t)row * DM + ((k8 >> 2) << 5) + sw) = o;
}

// ===========================================================================
// ------------------- round-1 fp32 fallback (small ws) ----------------------
// ===========================================================================
__global__ __launch_bounds__(256, 2) void gemm_nt_bias(
    const float* __restrict__ A, const float* __restrict__ Bm,
    const float* __restrict__ bias, float* __restrict__ C,
    int M, int N, int Kd)
{
    __shared__ float As[16][68];
    __shared__ float Bs[16][68];
    const int tid = threadIdx.x;
    const int tx = tid & 15, ty = tid >> 4;
    const int r0 = blockIdx.y << 6, c0 = blockIdx.x << 6;
    const int lr = tid >> 2, k4 = (tid & 3) << 2;
    const float* Ap = A  + (size_t)(r0 + lr) * Kd + k4;
    const float* Bp = Bm + (size_t)(c0 + lr) * Kd + k4;
    float acc[4][4];
#pragma unroll
    for (int i = 0; i < 4; ++i)
#pragma unroll
        for (int j = 0; j < 4; ++j) acc[i][j] = 0.f;
    for (int d0 = 0; d0 < Kd; d0 += 16) {
        float4 av = *(const float4*)(Ap + d0);
        float4 bv = *(const float4*)(Bp + d0);
        As[k4 + 0][lr] = av.x; As[k4 + 1][lr] = av.y;
        As[k4 + 2][lr] = av.z; As[k4 + 3][lr] = av.w;
        Bs[k4 + 0][lr] = bv.x; Bs[k4 + 1][lr] = bv.y;
        Bs[k4 + 2][lr] = bv.z; Bs[k4 + 3][lr] = bv.w;
        __syncthreads();
#pragma unroll
        for (int dd = 0; dd < 16; ++dd) {
            float4 a4 = *(const float4*)&As[dd][ty << 2];
            float4 b4 = *(const float4*)&Bs[dd][tx << 2];
            float ar[4] = {a4.x, a4.y, a4.z, a4.w};
            float br[4] = {b4.x, b4.y, b4.z, b4.w};
#pragma unroll
            for (int i = 0; i < 4; ++i)
#pragma unroll
                for (int j = 0; j < 4; ++j)
                    acc[i][j] = fmaf(ar[i], br[j], acc[i][j]);
        }
        __syncthreads();
    }
#pragma unroll
    for (int i = 0; i < 4; ++i) {
        float4 o;
        const int c = c0 + (tx << 2);
        o.x = acc[i][0] + bias[c + 0];
        o.y = acc[i][1] + bias[c + 1];
        o.z = acc[i][2] + bias[c + 2];
        o.w = acc[i][3] + bias[c + 3];
        *(float4*)&C[(size_t)(r0 + (ty << 2) + i) * N + c] = o;
    }
}

__device__ __forceinline__ void tile_gemm_f32(
    const float* __restrict__ xb, int src, bool ok,
    const float* __restrict__ wrow,
    int lr, int k4, int tx, int ty,
    float (&As)[16][68], float (&Ws)[16][68], float (&acc)[4][4])
{
#pragma unroll
    for (int i = 0; i < 4; ++i)
#pragma unroll
        for (int j = 0; j < 4; ++j) acc[i][j] = 0.f;
    const float* xrow = xb + (size_t)(ok ? src : 0) * DM + k4;
    for (int d0 = 0; d0 < DM; d0 += 16) {
        float4 av = make_float4(0.f, 0.f, 0.f, 0.f);
        if (ok) av = *(const float4*)(xrow + d0);
        float4 wv = *(const float4*)(wrow + d0);
        As[k4 + 0][lr] = av.x; As[k4 + 1][lr] = av.y;
        As[k4 + 2][lr] = av.z; As[k4 + 3][lr] = av.w;
        Ws[k4 + 0][lr] = wv.x; Ws[k4 + 1][lr] = wv.y;
        Ws[k4 + 2][lr] = wv.z; Ws[k4 + 3][lr] = wv.w;
        __syncthreads();
#pragma unroll
        for (int dd = 0; dd < 16; ++dd) {
            float4 a4 = *(const float4*)&As[dd][ty << 2];
            float4 b4 = *(const float4*)&Ws[dd][tx << 2];
            float ar[4] = {a4.x, a4.y, a4.z, a4.w};
            float br[4] = {b4.x, b4.y, b4.z, b4.w};
#pragma unroll
            for (int i = 0; i < 4; ++i)
#pragma unroll
                for (int j = 0; j < 4; ++j)
                    acc[i][j] = fmaf(ar[i], br[j], acc[i][j]);
        }
        __syncthreads();
    }
}

__global__ __launch_bounds__(256, 2) void attn_kernel(
    const float* __restrict__ x, const float* __restrict__ q,
    const float* __restrict__ Wk, const float* __restrict__ bk,
    const float* __restrict__ Wv, const float* __restrict__ bv,
    float* __restrict__ attn)
{
    __shared__ float As[16][68];
    __shared__ float Ws[16][68];
    __shared__ float qs[64][68];
    __shared__ float lg[64][17];
    __shared__ float red[64][17];
    const int tid = threadIdx.x;
    const int tx = tid & 15, ty = tid >> 4;
    const int bid = blockIdx.x;
    const int h = bid & 7, t = (bid >> 3) & 15, b = bid >> 7;
    const int l0 = t << 6;
    const int dil = c_dil[h];
    const int lr = tid >> 2, k4 = (tid & 3) << 2;
    for (int i = tid; i < 64 * 16; i += 256) {
        int l = i >> 4, o4 = (i & 15) << 2;
        float4 v = *(const float4*)&q[((size_t)(b * LL + l0 + l) * HH + h) * HW + o4];
        *(float4*)&qs[l][o4] = v;
    }
    const float* xb  = x  + (size_t)b * LL * DM;
    const float* Wkh = Wk + (size_t)h * KT * HW * DM;
    const float* Wvh = Wv + (size_t)h * KT * HW * DM;
    const float* bkh = bk + h * KT * HW;
    const float* bvh = bv + h * KT * HW;
    float acc[4][4];
    for (int kk = 0; kk < KT; ++kk) {
        const int src = l0 + lr - (KT - 1 - kk) * dil;
        const bool ok = (src >= 0) && (src < LL);
        tile_gemm_f32(xb, src, ok, Wkh + (size_t)(kk * HW + lr) * DM + k4,
                      lr, k4, tx, ty, As, Ws, acc);
        const float* bkp = bkh + kk * HW + (tx << 2);
#pragma unroll
        for (int i = 0; i < 4; ++i) {
            float p = 0.f;
#pragma unroll
            for (int j = 0; j < 4; ++j)
                p += (acc[i][j] + bkp[j]) * qs[(ty << 2) + i][(tx << 2) + j];
            red[(ty << 2) + i][tx] = p;
        }
        __syncthreads();
        if (tid < 64) {
            float s = 0.f;
#pragma unroll
            for (int u = 0; u < 16; ++u) s += red[tid][u];
            lg[tid][kk] = s;
        }
        __syncthreads();
    }
    if (tid < 64) {
        float m = lg[tid][0];
#pragma unroll
        for (int u = 1; u < KT; ++u) m = fmaxf(m, lg[tid][u]);
        float s = 0.f;
#pragma unroll
        for (int u = 0; u < KT; ++u) {
            float e = expf(lg[tid][u] - m);
            lg[tid][u] = e; s += e;
        }
        float inv = 1.f / s;
#pragma unroll
        for (int u = 0; u < KT; ++u) lg[tid][u] *= inv;
    }
    __syncthreads();
    float vacc[4][4];
#pragma unroll
    for (int i = 0; i < 4; ++i)
#pragma unroll
        for (int j = 0; j < 4; ++j) vacc[i][j] = 0.f;
    for (int kk = 0; kk < KT; ++kk) {
        const int src = l0 + lr - (KT - 1 - kk) * dil;
        const bool ok = (src >= 0) && (src < LL);
        tile_gemm_f32(xb, src, ok, Wvh + (size_t)(kk * HW + lr) * DM + k4,
                      lr, k4, tx, ty, As, Ws, acc);
        const float* bvp = bvh + kk * HW + (tx << 2);
#pragma unroll
        for (int i = 0; i < 4; ++i) {
            float sc = lg[(ty << 2) + i][kk];
#pragma unroll
            for (int j = 0; j < 4; ++j)
                vacc[i][j] = fmaf(sc, acc[i][j] + bvp[j], vacc[i][j]);
        }
    }
#pragma unroll
    for (int i = 0; i < 4; ++i) {
        float4 o;
        o.x = vacc[i][0] * 0.125f;
        o.y = vacc[i][1] * 0.125f;
        o.z = vacc[i][2] * 0.125f;
        o.w = vacc[i][3] * 0.125f;
        *(float4*)&attn[((size_t)(b * LL + l0 + (ty << 2) + i) * HH + h) * HW + (tx << 2)] = o;
    }
}

// ===========================================================================
extern "C" void kernel_launch(void* const* d_in, const int* in_sizes, int n_in,
                              void* d_out, int out_size, void* d_ws, size_t ws_size,
                              hipStream_t stream)
{
    const float* x  = (const float*)d_in[0];
    const float* Wq = (const float*)d_in[1];
    const float* bq = (const float*)d_in[2];
    const float* Wk = (const float*)d_in[3];
    const float* bk = (const float*)d_in[4];
    const float* Wv = (const float*)d_in[5];
    const float* bv = (const float*)d_in[6];
    const float* Wo = (const float*)d_in[7];
    const float* bo = (const float*)d_in[8];
    float* out = (float*)d_out;

    const int M = BD * LL;  // 2048

    // ws layout (ushort elements) for the fast path
    const size_t N_X   = (size_t)BD * LL * DM;            //  1,048,576
    const size_t N_WB  = (size_t)NQKV * DM;               //  8,650,752
    const size_t N_WO  = (size_t)DM * DM;                 //    262,144
    const size_t N_QKV = (size_t)M * NQKV;                // 34,603,008
    const size_t NEED  = (N_X + N_WB + N_WO + N_QKV + N_X) * 2;

    if (ws_size >= NEED) {
        u16* xb    = (u16*)d_ws;
        u16* wb    = xb    + N_X;      // [Wq|Wk|Wv] swizzled, 16896 x 512
        u16* wob   = wb    + N_WB;
        u16* qkv   = wob   + N_WO;     // natural row-major 2048 x 16896
        u16* attnb = qkv   + N_QKV;

        cvt_swz<<<4864, 256, 0, stream>>>(x, Wq, Wk, Wv, Wo, xb, wb, wob);

        // qkv = x * [Wq|Wk|Wv]^T + bias (natural layout)
        gemm_bf16<<<dim3(136, 16), 256, 0, stream>>>(
            xb, wb, bq, bk, bv, qkv);

        // two-phase register-resident gather -> attnb (swizzled)
        attn_bf16<<<BD * HH * (LL / 32), 256, 0, stream>>>(
            qkv, bk, bv, attnb);

        // out = attnb * Wo^T + bo -> fp32
        gemm_out<<<dim3(8, 32), 256, 0, stream>>>(attnb, wob, bo, out);
    } else {
        // fp32 fallback (round-1 path, 8 MB ws)
        float* qws = (float*)d_ws;
        float* aws = qws + (size_t)BD * LL * HH * HW;
        gemm_nt_bias<<<dim3((HH * HW) / 64, M / 64), 256, 0, stream>>>(
            x, Wq, bq, qws, M, HH * HW, DM);
        attn_kernel<<<BD * HH * (LL / 64), 256, 0, stream>>>(
            x, qws, Wk, bk, Wv, bv, aws);
        gemm_nt_bias<<<dim3(DM / 64, M / 64), 256, 0, stream>>>(
            aws, Wo, bo, out, M, DM, HH * HW);
    }
}